// Round 2
// baseline (252.925 us; speedup 1.0000x reference)
//
#include <hip/hip_runtime.h>
#include <math.h>

// Quadrotor dynamics, B=2^20 independent 32-float AoS rows.
// R1: coalesced LDS staging (247.8 us total, kernel ~88 us).
// R2: RK4 accumulator + 7-state integration + LDS passthrough ->
//     VGPR 52, kernel ~85 us, but: occupancy 32% (LDS-capped at 4 blk/CU),
//     3.7M LDS bank-conflict cycles (stride-36 scalar reads are 8-way),
//     VALUBusy 21%, HBM 30% -> latency-bound.
// R3 (this): (a) LDS row stride 36->32 floats (32 KB/block -> 5 blocks/CU,
//     exactly 160 KB), (b) XOR column swizzle pc = lc ^ (t&7) on float4
//     slots: every 8-lane group covers all 32 banks, all LDS ops b128,
//     zero conflicts, (c) stage-in via global_load_lds width=16 with
//     inverse-swizzled per-lane GLOBAL source (linear LDS dest), so the
//     transpose costs no VGPR round-trip and loads are async.

#define INV_MASSF  (1.0f / 1.5f)
#define GRAVF      9.81f
#define KDF        0.1f
#define KHF        0.01f
#define JXF        0.0211f
#define JYF        0.0219f
#define JZF        0.0366f
#define JIXF       (1.0f / 0.0211f)
#define JIYF       (1.0f / 0.0219f)
#define JIZF       (1.0f / 0.0366f)
#define PI_2F      1.57079632679489661923f

#define ROWS    256          // threads (rows) per block
#define RSTR    32           // LDS row stride in floats (128B, swizzled)

__device__ __forceinline__ float clamp1(float x) {
    return fminf(fmaxf(x, -1.0f), 1.0f);
}

// derivative of the coupled 7-state block: x = {qw,qx,qy,qz, p,q,r}
__device__ __forceinline__ void qw_deriv(const float x[7],
                                         float mx, float my, float mz,
                                         float k[7]) {
    const float ew = x[0], ex = x[1], ey = x[2], ez = x[3];
    const float p = x[4], q = x[5], r = x[6];
    k[0] = 0.5f * (-ex * p - ey * q - ez * r);
    k[1] = 0.5f * ( ew * p + ey * r - ez * q);
    k[2] = 0.5f * ( ew * q - ex * r + ez * p);
    k[3] = 0.5f * ( ew * r + ex * q - ey * p);
    const float Jwx = JXF * p, Jwy = JYF * q, Jwz = JZF * r;
    k[4] = (mx - (q * Jwz - r * Jwy)) * JIXF;
    k[5] = (my - (r * Jwx - p * Jwz)) * JIYF;
    k[6] = (mz - (p * Jwy - q * Jwx)) * JIZF;
}

// full per-row physics: logical s[32] in, logical o[32] out
__device__ __forceinline__ void qd_compute(const float s[32], float4 dl,
                                           const float* __restrict__ G1,
                                           float dt, float o[32]) {
    // ---- motor mixing: tt = G1 @ clip(delta)^2 ----
    float T, Mx, My, Mz;
    {
        float d0 = fminf(fmaxf(dl.x, 0.0f), 1000.0f);
        float d1 = fminf(fmaxf(dl.y, 0.0f), 1000.0f);
        float d2 = fminf(fmaxf(dl.z, 0.0f), 1000.0f);
        float d3 = fminf(fmaxf(dl.w, 0.0f), 1000.0f);
        d0 *= d0; d1 *= d1; d2 *= d2; d3 *= d3;
        const float4* g4 = (const float4*)G1;
        const float4 g0 = g4[0], g1 = g4[1], g2 = g4[2], g3 = g4[3];
        T  = g0.x * d0 + g0.y * d1 + g0.z * d2 + g0.w * d3;
        Mx = g1.x * d0 + g1.y * d1 + g1.z * d2 + g1.w * d3;
        My = g2.x * d0 + g2.y * d1 + g2.z * d2 + g2.w * d3;
        Mz = g3.x * d0 + g3.y * d1 + g3.z * d2 + g3.w * d3;
    }

    const float ew = s[9], ex = s[10], ey = s[11], ez = s[12];

    // rotation matrix from ORIGINAL quaternion
    const float r00 = ew*ew + ex*ex - ey*ey - ez*ez;
    const float r01 = 2.0f * (ex*ey - ew*ez);
    const float r02 = 2.0f * (ex*ez + ew*ey);
    const float r10 = 2.0f * (ex*ey + ew*ez);
    const float r11 = ew*ew - ex*ex + ey*ey - ez*ez;
    const float r12 = 2.0f * (ey*ez - ew*ex);
    const float r20 = 2.0f * (ex*ez - ew*ey);
    const float r21 = 2.0f * (ey*ez + ew*ex);
    const float r22 = ew*ew - ex*ex - ey*ey + ez*ez;

    // wind in body frame: R^T @ wind
    const float vwb0 = r00 * s[28] + r10 * s[29] + r20 * s[30];
    const float vwb1 = r01 * s[28] + r11 * s[29] + r21 * s[30];
    const float vwb2 = r02 * s[28] + r12 * s[29] + r22 * s[30];

    const float u_r = s[16] - vwb0;
    const float v_r = s[17] - vwb1;
    const float w_r = s[18] - vwb2;
    const float Va = sqrtf(u_r * u_r + v_r * v_r + w_r * w_r);
    const float alpha = (u_r == 0.0f) ? PI_2F : atan2f(w_r, u_r);
    const float beta  = (Va == 0.0f) ? 0.0f : asinf(clamp1(v_r / Va));

    // body forces -> inertial; v_dot is constant across all RK4 stages
    const float fx = -KDF * u_r;
    const float fy = -KDF * v_r;
    const float fz = -T - KDF * w_r + KHF * (u_r * u_r + v_r * v_r);
    const float vd0 = (r00 * fx + r01 * fy + r02 * fz) * INV_MASSF;
    const float vd1 = (r10 * fx + r11 * fy + r12 * fz) * INV_MASSF;
    const float vd2 = (r20 * fx + r21 * fy + r22 * fz) * INV_MASSF + GRAVF;

    // exact RK4 closed forms for pos/v (v_dot stage-constant)
    const float vn0 = s[13] + dt * vd0;
    const float vn1 = s[14] + dt * vd1;
    const float vn2 = s[15] + dt * vd2;
    const float hdt2 = 0.5f * dt * dt;
    const float pn0 = s[3] + dt * s[13] + hdt2 * vd0;
    const float pn1 = s[4] + dt * s[14] + hdt2 * vd1;
    const float pn2 = s[5] + dt * s[15] + hdt2 * vd2;

    // ---- RK4 on the coupled 7 states (accumulator form) ----
    const float h2 = 0.5f * dt;
    float x0[7] = {ew, ex, ey, ez, s[19], s[20], s[21]};
    float k[7], acc[7], xt[7], xn[7];
    qw_deriv(x0, Mx, My, Mz, k);
    #pragma unroll
    for (int i = 0; i < 7; ++i) { acc[i] = k[i]; xt[i] = x0[i] + h2 * k[i]; }
    qw_deriv(xt, Mx, My, Mz, k);
    #pragma unroll
    for (int i = 0; i < 7; ++i) { acc[i] += 2.0f * k[i]; xt[i] = x0[i] + h2 * k[i]; }
    qw_deriv(xt, Mx, My, Mz, k);
    #pragma unroll
    for (int i = 0; i < 7; ++i) { acc[i] += 2.0f * k[i]; xt[i] = x0[i] + dt * k[i]; }
    qw_deriv(xt, Mx, My, Mz, k);
    const float dt6 = dt / 6.0f;
    #pragma unroll
    for (int i = 0; i < 7; ++i) xn[i] = x0[i] + dt6 * (acc[i] + k[i]);

    // ---- normalize new quaternion ----
    float qw2 = xn[0], qx2 = xn[1], qy2 = xn[2], qz2 = xn[3];
    const float qi = 1.0f / sqrtf(qw2*qw2 + qx2*qx2 + qy2*qy2 + qz2*qz2);
    qw2 *= qi; qx2 *= qi; qy2 *= qi; qz2 *= qi;

    // ---- euler angles from NEW quaternion ----
    const float phi = atan2f(2.0f * (qw2 * qx2 + qy2 * qz2),
                             qw2*qw2 + qz2*qz2 - qx2*qx2 - qy2*qy2);
    const float theta = asinf(clamp1(2.0f * (qw2 * qy2 - qx2 * qz2)));
    const float psi = atan2f(2.0f * (qw2 * qz2 + qx2 * qy2),
                             qw2*qw2 + qx2*qx2 - qy2*qy2 - qz2*qz2);

    // ---- ground speed from ORIGINAL R and body velocity ----
    const float p0 = r00 * s[16] + r01 * s[17] + r02 * s[18];
    const float p1 = r10 * s[16] + r11 * s[17] + r12 * s[18];
    const float p2 = r20 * s[16] + r21 * s[17] + r22 * s[18];
    const float Vg = sqrtf(p0 * p0 + p1 * p1 + p2 * p2);
    const float vgs = (Vg == 0.0f) ? 1.0f : Vg;
    const float gamma = asinf(clamp1(p2 / vgs));
    const float chi = atan2f(p1, p0);

    // ---- assemble output row ----
    o[0] = s[0]; o[1] = s[1]; o[2] = s[2];
    o[3] = pn0; o[4] = pn1; o[5] = pn2;
    o[6] = phi; o[7] = theta; o[8] = psi;
    o[9] = qw2; o[10] = qx2; o[11] = qy2; o[12] = qz2;
    o[13] = vn0; o[14] = vn1; o[15] = vn2;
    o[16] = s[16]; o[17] = s[17]; o[18] = s[18];
    o[19] = xn[4]; o[20] = xn[5]; o[21] = xn[6];
    o[22] = Va; o[23] = Vg;
    o[24] = alpha; o[25] = beta;
    o[26] = gamma; o[27] = chi;
    o[28] = s[28]; o[29] = s[29]; o[30] = s[30]; o[31] = s[31];
}

__global__ __launch_bounds__(ROWS, 5) void qd_dynamics_kernel(
    const float* __restrict__ state,
    const float* __restrict__ delta,
    const float* __restrict__ G1,
    const float* __restrict__ dtp,
    float* __restrict__ out,
    int B)
{
    // 32 KB -> 5 blocks/CU (exactly 160 KB). Physical float4 slot (r, pc)
    // holds logical column pc ^ (r&7) of row r (XOR involution).
    __shared__ __align__(16) float lds[ROWS * RSTR];

    const int tid = threadIdx.x;
    const int row0 = blockIdx.x * ROWS;
    const bool full = (row0 + ROWS) <= B;

    const float dt = dtp[0];

    float s[32], o[32];
    float4 dl;

    if (full) {
        // ---- async stage-in: linear LDS dest, inverse-swizzled global src.
        // Slot f4=(r,c4) <- global float4 (row0+r, c4^(r&7)); every 8-lane
        // group reads one 128B row (permuted within the line -> coalesced).
        const float* gbase = state + (size_t)row0 * 32;
        #pragma unroll
        for (int i = 0; i < 8; ++i) {
            const int f4 = i * ROWS + tid;       // linear LDS float4 slot
            const int r  = f4 >> 3;
            const int c4 = f4 & 7;
            const int sc = c4 ^ (r & 7);         // swizzled source column
            __builtin_amdgcn_global_load_lds(
                (const __attribute__((address_space(1))) void*)
                    (gbase + (size_t)r * 32 + sc * 4),
                (__attribute__((address_space(3))) void*)(&lds[f4 * 4]),
                16, 0, 0);
        }
        dl = ((const float4*)delta)[row0 + tid];
        __syncthreads();                          // drains vmcnt

        // ---- own-row read, swizzled: physical slot lc^(tid&7) holds lc.
        // bank start = 4*(lc^(t&7)): distinct across each 8-lane group.
        #pragma unroll
        for (int lc = 0; lc < 8; ++lc)
            ((float4*)s)[lc] =
                *(const float4*)&lds[(tid * 8 + (lc ^ (tid & 7))) * 4];
    } else {
        const int b = row0 + tid;
        const int bb = (b < B) ? b : (B - 1);
        const float4* sp = (const float4*)(state + (size_t)bb * 32);
        #pragma unroll
        for (int i = 0; i < 8; ++i) ((float4*)s)[i] = sp[i];
        dl = ((const float4*)delta)[bb];
    }

    qd_compute(s, dl, G1, dt, o);

    if (full) {
        // thread t owns LDS row t in both phases -> no barrier before write
        #pragma unroll
        for (int lc = 0; lc < 8; ++lc)
            *(float4*)&lds[(tid * 8 + (lc ^ (tid & 7))) * 4] =
                ((const float4*)o)[lc];
        __syncthreads();
        // ---- coalesced stage-out: linear LDS read, swizzled global dest
        float4* op4 = (float4*)(out + (size_t)row0 * 32);
        #pragma unroll
        for (int i = 0; i < 8; ++i) {
            const int f4 = i * ROWS + tid;
            const int r  = f4 >> 3;
            const int c4 = f4 & 7;
            const int sc = c4 ^ (r & 7);
            op4[(size_t)r * 8 + sc] = *(const float4*)&lds[f4 * 4];
        }
    } else {
        const int b = row0 + tid;
        if (b < B) {
            float4* op = (float4*)(out + (size_t)b * 32);
            #pragma unroll
            for (int i = 0; i < 8; ++i) op[i] = ((const float4*)o)[i];
        }
    }
}

extern "C" void kernel_launch(void* const* d_in, const int* in_sizes, int n_in,
                              void* d_out, int out_size, void* d_ws, size_t ws_size,
                              hipStream_t stream) {
    const float* state = (const float*)d_in[0];
    const float* delta = (const float*)d_in[1];
    const float* G1    = (const float*)d_in[2];
    const float* dtp   = (const float*)d_in[3];
    float* out = (float*)d_out;
    const int B = in_sizes[0] / 32;
    const int grid = (B + ROWS - 1) / ROWS;
    hipLaunchKernelGGL(qd_dynamics_kernel, dim3(grid), dim3(ROWS), 0, stream,
                       state, delta, G1, dtp, out, B);
}

// Round 3
// 248.828 us; speedup vs baseline: 1.0165x; 1.0165x over previous
//
#include <hip/hip_runtime.h>
#include <math.h>

// Quadrotor dynamics, B=2^20 independent 32-float AoS rows.
// R1: coalesced LDS staging (kernel ~88 us).
// R2: RK4 accumulator + 7-state integration -> VGPR 52, ~85.7 us.
//     Latency-bound: occupancy 32%, VALU 21%, HBM 30%.
// R3: XOR-swizzled LDS + 5 blocks/CU: conflicts -80% BUT swizzled GLOBAL
//     store addresses caused +34% WRITE_SIZE (partial-sector write amp);
//     dur flat at 88.6 us. Lesson: global addresses must stay lane-linear.
// R4 (this): barrier-FREE structure. Each wave owns a private 64-row x
//     128B LDS region (8 KB; 32 KB/block, 5 blocks/CU): the global<->LDS
//     transpose is wave-local, so no __syncthreads anywhere. Waves free-run
//     and overlap their load/compute/store phases instead of convoying.
//     Swizzle lives ONLY on the LDS side: stage-in via global_load_lds
//     (linear LDS dest, row-permuted global SOURCE), stage-out ds_read at
//     swizzled addr -> lane-linear global stores (write-amp fixed).

#define INV_MASSF  (1.0f / 1.5f)
#define GRAVF      9.81f
#define KDF        0.1f
#define KHF        0.01f
#define JXF        0.0211f
#define JYF        0.0219f
#define JZF        0.0366f
#define JIXF       (1.0f / 0.0211f)
#define JIYF       (1.0f / 0.0219f)
#define JIZF       (1.0f / 0.0366f)
#define PI_2F      1.57079632679489661923f

#define ROWS    256          // threads per block (4 independent waves)
#define WROWS   64           // rows per wave

__device__ __forceinline__ float clamp1(float x) {
    return fminf(fmaxf(x, -1.0f), 1.0f);
}

// derivative of the coupled 7-state block: x = {qw,qx,qy,qz, p,q,r}
__device__ __forceinline__ void qw_deriv(const float x[7],
                                         float mx, float my, float mz,
                                         float k[7]) {
    const float ew = x[0], ex = x[1], ey = x[2], ez = x[3];
    const float p = x[4], q = x[5], r = x[6];
    k[0] = 0.5f * (-ex * p - ey * q - ez * r);
    k[1] = 0.5f * ( ew * p + ey * r - ez * q);
    k[2] = 0.5f * ( ew * q - ex * r + ez * p);
    k[3] = 0.5f * ( ew * r + ex * q - ey * p);
    const float Jwx = JXF * p, Jwy = JYF * q, Jwz = JZF * r;
    k[4] = (mx - (q * Jwz - r * Jwy)) * JIXF;
    k[5] = (my - (r * Jwx - p * Jwz)) * JIYF;
    k[6] = (mz - (p * Jwy - q * Jwx)) * JIZF;
}

// full per-row physics: logical s[32] in, logical o[32] out
__device__ __forceinline__ void qd_compute(const float s[32], float4 dl,
                                           const float* __restrict__ G1,
                                           float dt, float o[32]) {
    // ---- motor mixing: tt = G1 @ clip(delta)^2 ----
    float T, Mx, My, Mz;
    {
        float d0 = fminf(fmaxf(dl.x, 0.0f), 1000.0f);
        float d1 = fminf(fmaxf(dl.y, 0.0f), 1000.0f);
        float d2 = fminf(fmaxf(dl.z, 0.0f), 1000.0f);
        float d3 = fminf(fmaxf(dl.w, 0.0f), 1000.0f);
        d0 *= d0; d1 *= d1; d2 *= d2; d3 *= d3;
        const float4* g4 = (const float4*)G1;
        const float4 g0 = g4[0], g1 = g4[1], g2 = g4[2], g3 = g4[3];
        T  = g0.x * d0 + g0.y * d1 + g0.z * d2 + g0.w * d3;
        Mx = g1.x * d0 + g1.y * d1 + g1.z * d2 + g1.w * d3;
        My = g2.x * d0 + g2.y * d1 + g2.z * d2 + g2.w * d3;
        Mz = g3.x * d0 + g3.y * d1 + g3.z * d2 + g3.w * d3;
    }

    const float ew = s[9], ex = s[10], ey = s[11], ez = s[12];

    // rotation matrix from ORIGINAL quaternion
    const float r00 = ew*ew + ex*ex - ey*ey - ez*ez;
    const float r01 = 2.0f * (ex*ey - ew*ez);
    const float r02 = 2.0f * (ex*ez + ew*ey);
    const float r10 = 2.0f * (ex*ey + ew*ez);
    const float r11 = ew*ew - ex*ex + ey*ey - ez*ez;
    const float r12 = 2.0f * (ey*ez - ew*ex);
    const float r20 = 2.0f * (ex*ez - ew*ey);
    const float r21 = 2.0f * (ey*ez + ew*ex);
    const float r22 = ew*ew - ex*ex - ey*ey + ez*ez;

    // wind in body frame: R^T @ wind
    const float vwb0 = r00 * s[28] + r10 * s[29] + r20 * s[30];
    const float vwb1 = r01 * s[28] + r11 * s[29] + r21 * s[30];
    const float vwb2 = r02 * s[28] + r12 * s[29] + r22 * s[30];

    const float u_r = s[16] - vwb0;
    const float v_r = s[17] - vwb1;
    const float w_r = s[18] - vwb2;
    const float Va = sqrtf(u_r * u_r + v_r * v_r + w_r * w_r);
    const float alpha = (u_r == 0.0f) ? PI_2F : atan2f(w_r, u_r);
    const float beta  = (Va == 0.0f) ? 0.0f : asinf(clamp1(v_r / Va));

    // body forces -> inertial; v_dot is constant across all RK4 stages
    const float fx = -KDF * u_r;
    const float fy = -KDF * v_r;
    const float fz = -T - KDF * w_r + KHF * (u_r * u_r + v_r * v_r);
    const float vd0 = (r00 * fx + r01 * fy + r02 * fz) * INV_MASSF;
    const float vd1 = (r10 * fx + r11 * fy + r12 * fz) * INV_MASSF;
    const float vd2 = (r20 * fx + r21 * fy + r22 * fz) * INV_MASSF + GRAVF;

    // exact RK4 closed forms for pos/v (v_dot stage-constant)
    const float vn0 = s[13] + dt * vd0;
    const float vn1 = s[14] + dt * vd1;
    const float vn2 = s[15] + dt * vd2;
    const float hdt2 = 0.5f * dt * dt;
    const float pn0 = s[3] + dt * s[13] + hdt2 * vd0;
    const float pn1 = s[4] + dt * s[14] + hdt2 * vd1;
    const float pn2 = s[5] + dt * s[15] + hdt2 * vd2;

    // ---- RK4 on the coupled 7 states (accumulator form) ----
    const float h2 = 0.5f * dt;
    float x0[7] = {ew, ex, ey, ez, s[19], s[20], s[21]};
    float k[7], acc[7], xt[7], xn[7];
    qw_deriv(x0, Mx, My, Mz, k);
    #pragma unroll
    for (int i = 0; i < 7; ++i) { acc[i] = k[i]; xt[i] = x0[i] + h2 * k[i]; }
    qw_deriv(xt, Mx, My, Mz, k);
    #pragma unroll
    for (int i = 0; i < 7; ++i) { acc[i] += 2.0f * k[i]; xt[i] = x0[i] + h2 * k[i]; }
    qw_deriv(xt, Mx, My, Mz, k);
    #pragma unroll
    for (int i = 0; i < 7; ++i) { acc[i] += 2.0f * k[i]; xt[i] = x0[i] + dt * k[i]; }
    qw_deriv(xt, Mx, My, Mz, k);
    const float dt6 = dt / 6.0f;
    #pragma unroll
    for (int i = 0; i < 7; ++i) xn[i] = x0[i] + dt6 * (acc[i] + k[i]);

    // ---- normalize new quaternion ----
    float qw2 = xn[0], qx2 = xn[1], qy2 = xn[2], qz2 = xn[3];
    const float qi = 1.0f / sqrtf(qw2*qw2 + qx2*qx2 + qy2*qy2 + qz2*qz2);
    qw2 *= qi; qx2 *= qi; qy2 *= qi; qz2 *= qi;

    // ---- euler angles from NEW quaternion ----
    const float phi = atan2f(2.0f * (qw2 * qx2 + qy2 * qz2),
                             qw2*qw2 + qz2*qz2 - qx2*qx2 - qy2*qy2);
    const float theta = asinf(clamp1(2.0f * (qw2 * qy2 - qx2 * qz2)));
    const float psi = atan2f(2.0f * (qw2 * qz2 + qx2 * qy2),
                             qw2*qw2 + qx2*qx2 - qy2*qy2 - qz2*qz2);

    // ---- ground speed from ORIGINAL R and body velocity ----
    const float p0 = r00 * s[16] + r01 * s[17] + r02 * s[18];
    const float p1 = r10 * s[16] + r11 * s[17] + r12 * s[18];
    const float p2 = r20 * s[16] + r21 * s[17] + r22 * s[18];
    const float Vg = sqrtf(p0 * p0 + p1 * p1 + p2 * p2);
    const float vgs = (Vg == 0.0f) ? 1.0f : Vg;
    const float gamma = asinf(clamp1(p2 / vgs));
    const float chi = atan2f(p1, p0);

    // ---- assemble output row ----
    o[0] = s[0]; o[1] = s[1]; o[2] = s[2];
    o[3] = pn0; o[4] = pn1; o[5] = pn2;
    o[6] = phi; o[7] = theta; o[8] = psi;
    o[9] = qw2; o[10] = qx2; o[11] = qy2; o[12] = qz2;
    o[13] = vn0; o[14] = vn1; o[15] = vn2;
    o[16] = s[16]; o[17] = s[17]; o[18] = s[18];
    o[19] = xn[4]; o[20] = xn[5]; o[21] = xn[6];
    o[22] = Va; o[23] = Vg;
    o[24] = alpha; o[25] = beta;
    o[26] = gamma; o[27] = chi;
    o[28] = s[28]; o[29] = s[29]; o[30] = s[30]; o[31] = s[31];
}

__global__ __launch_bounds__(ROWS, 5) void qd_dynamics_kernel(
    const float* __restrict__ state,
    const float* __restrict__ delta,
    const float* __restrict__ G1,
    const float* __restrict__ dtp,
    float* __restrict__ out,
    int B)
{
    // 4 waves x private 8KB region = 32 KB -> 5 blocks/CU (160 KB exact).
    // Within a region: physical float4 slot (r, pc) holds logical column
    // pc ^ (r&7) of local row r (XOR involution; r = lane).
    __shared__ __align__(16) float lds[ROWS * 32];

    const int tid  = threadIdx.x;
    const int lane = tid & 63;
    const int wv   = tid >> 6;
    const int row0 = blockIdx.x * ROWS;
    const int wrow0 = row0 + wv * WROWS;      // this wave's first global row
    float* lw = &lds[wv * (WROWS * 32)];      // this wave's LDS region
    const bool full = (row0 + ROWS) <= B;

    const float dt = dtp[0];

    float s[32], o[32];
    float4 dl;

    if (full) {
        // ---- async stage-in, wave-local, NO barrier ----
        // Linear LDS dest (uniform base + lane*16 per HW), row-permuted
        // global source: slot (r,c4) <- global float4 (wrow0+r, c4^(r&7)).
        // Per instruction the wave reads 8 full rows = 1KB contiguous.
        const float* gb = state + (size_t)wrow0 * 32;
        #pragma unroll
        for (int i = 0; i < 8; ++i) {
            const int slot = i * 64 + lane;
            const int r  = slot >> 3;
            const int c4 = slot & 7;
            const int sc = c4 ^ (r & 7);
            __builtin_amdgcn_global_load_lds(
                (const __attribute__((address_space(1))) void*)
                    (gb + (size_t)r * 32 + sc * 4),
                (__attribute__((address_space(3))) void*)(lw + i * 256),
                16, 0, 0);
        }
        dl = ((const float4*)delta)[row0 + tid];   // overlaps DMA latency
        asm volatile("s_waitcnt vmcnt(0)" ::: "memory");

        // ---- own-row read, swizzled: physical slot lc^(lane&7) holds lc.
        #pragma unroll
        for (int lc = 0; lc < 8; ++lc)
            ((float4*)s)[lc] =
                *(const float4*)&lw[(lane * 8 + (lc ^ (lane & 7))) * 4];
    } else {
        const int b = row0 + tid;
        const int bb = (b < B) ? b : (B - 1);
        const float4* sp = (const float4*)(state + (size_t)bb * 32);
        #pragma unroll
        for (int i = 0; i < 8; ++i) ((float4*)s)[i] = sp[i];
        dl = ((const float4*)delta)[bb];
    }

    qd_compute(s, dl, G1, dt, o);

    if (full) {
        // ---- own-row write, swizzled (same addresses as the read) ----
        #pragma unroll
        for (int lc = 0; lc < 8; ++lc)
            *(float4*)&lw[(lane * 8 + (lc ^ (lane & 7))) * 4] =
                ((const float4*)o)[lc];
        // ---- stage-out: swizzled LDS read -> LANE-LINEAR global store ----
        // (compiler inserts the lgkmcnt wait for the write->read aliasing;
        //  wave-local, so no barrier)
        float4* ob = (float4*)(out + (size_t)wrow0 * 32);
        #pragma unroll
        for (int i = 0; i < 8; ++i) {
            const int slot = i * 64 + lane;
            const int r  = slot >> 3;
            const int c4 = slot & 7;
            const int p  = r * 8 + (c4 ^ (r & 7));
            ob[slot] = *(const float4*)&lw[p * 4];
        }
    } else {
        const int b = row0 + tid;
        if (b < B) {
            float4* op = (float4*)(out + (size_t)b * 32);
            #pragma unroll
            for (int i = 0; i < 8; ++i) op[i] = ((const float4*)o)[i];
        }
    }
}

extern "C" void kernel_launch(void* const* d_in, const int* in_sizes, int n_in,
                              void* d_out, int out_size, void* d_ws, size_t ws_size,
                              hipStream_t stream) {
    const float* state = (const float*)d_in[0];
    const float* delta = (const float*)d_in[1];
    const float* G1    = (const float*)d_in[2];
    const float* dtp   = (const float*)d_in[3];
    float* out = (float*)d_out;
    const int B = in_sizes[0] / 32;
    const int grid = (B + ROWS - 1) / ROWS;
    hipLaunchKernelGGL(qd_dynamics_kernel, dim3(grid), dim3(ROWS), 0, stream,
                       state, delta, G1, dtp, out, B);
}